// Round 1
// baseline (733.336 us; speedup 1.0000x reference)
//
#include <hip/hip_runtime.h>
#include <cstdint>

#define AS1 __attribute__((address_space(1)))
#define AS3 __attribute__((address_space(3)))

typedef __attribute__((ext_vector_type(8))) short short8;
typedef __attribute__((ext_vector_type(4))) float floatx4;
typedef unsigned short u16;

static constexpr int NN   = 100000;
static constexpr int FF   = 512;
static constexpr int HH   = 128;
static constexpr int EE   = 1600000;
static constexpr int PADM = 100096;   // 782 * 128

__device__ __forceinline__ u16 f2bf_rne(float v) {
    uint32_t u = __builtin_bit_cast(uint32_t, v);
    u += 0x7fffu + ((u >> 16) & 1u);
    return (u16)(u >> 16);
}
__device__ __forceinline__ float bf2f(u16 h) {
    uint32_t u = ((uint32_t)h) << 16;
    return __builtin_bit_cast(float, u);
}

__device__ __forceinline__ void async16(const void* g, void* l) {
    __builtin_amdgcn_global_load_lds((AS1 const void*)g, (AS3 void*)l, 16, 0, 0);
}

// ---- split features into bf16 hi + lo --------------------------------------
__global__ void k_split_a(const float* __restrict__ A,
                          u16* __restrict__ hi, u16* __restrict__ lo) {
    int t = blockIdx.x * 256 + threadIdx.x;           // t < NN*FF/4
    float4 x = ((const float4*)A)[t];
    u16 h0 = f2bf_rne(x.x), h1 = f2bf_rne(x.y), h2 = f2bf_rne(x.z), h3 = f2bf_rne(x.w);
    ushort4 hv = { h0, h1, h2, h3 };
    ushort4 lv = { f2bf_rne(x.x - bf2f(h0)), f2bf_rne(x.y - bf2f(h1)),
                   f2bf_rne(x.z - bf2f(h2)), f2bf_rne(x.w - bf2f(h3)) };
    ((ushort4*)hi)[t] = hv;
    ((ushort4*)lo)[t] = lv;
}

// ---- build W^T = [Wm1|Ws1]^T as bf16 hi/lo, layout [n][k], n<128 miu -------
__global__ void k_split_w(const float* __restrict__ Wm1, const float* __restrict__ Ws1,
                          u16* __restrict__ whi, u16* __restrict__ wlo) {
    int t = blockIdx.x * 256 + threadIdx.x;           // t < 256*512
    int n = t >> 9, k = t & 511;
    float v = (n < HH) ? Wm1[k * HH + n] : Ws1[k * HH + (n - HH)];
    u16 h = f2bf_rne(v);
    whi[t] = h;
    wlo[t] = f2bf_rne(v - bf2f(h));
}

// ---- GEMM: P[M=100096p,256] = A[M,512] @ W[512,256] ------------------------
// blockIdx.x: 0 = miu cols (1-term bf16), 1 = sigma cols (3-term split bf16)
// blockIdx.y: row block (128 rows)
__global__ __launch_bounds__(256) void k_gemm(
        const u16* __restrict__ Ahi, const u16* __restrict__ Alo,
        const u16* __restrict__ Bhi, const u16* __restrict__ Blo,
        float* __restrict__ P) {
    __shared__ u16 lds[4][4096];   // 0=Ahi 1=Alo 2=Bhi 3=Blo, each 128x32 bf16

    const int tid  = threadIdx.x;
    const int wave = tid >> 6, lane = tid & 63;
    const int ml = lane & 15, quad = lane >> 4;
    const int rowBase = blockIdx.y * 128;
    const int colBase = blockIdx.x * 128;
    const bool SIG = (blockIdx.x == 1);
    const int waveRow = (wave & 1) * 64, waveCol = (wave >> 1) * 64;

    floatx4 acc[4][4];
#pragma unroll
    for (int i = 0; i < 4; i++)
#pragma unroll
        for (int j = 0; j < 4; j++) acc[i][j] = (floatx4){0.f, 0.f, 0.f, 0.f};

    // staging: chunk c = issue*256 + tid; row = c>>2; ko = (c&3)*8
    const int r0 = tid >> 2, ko = (tid & 3) * 8;
    const u16* gA0  = Ahi + (size_t)(rowBase + r0) * FF + ko;
    const u16* gA1  = gA0 + (size_t)64 * FF;
    const u16* gAl0 = Alo + (size_t)(rowBase + r0) * FF + ko;
    const u16* gAl1 = gAl0 + (size_t)64 * FF;
    const u16* gB0  = Bhi + (size_t)(colBase + r0) * FF + ko;
    const u16* gB1  = gB0 + (size_t)64 * FF;
    const u16* gBl0 = Blo + (size_t)(colBase + r0) * FF + ko;
    const u16* gBl1 = gBl0 + (size_t)64 * FF;
    const int ldst0 = wave * 512;          // ushort offsets (lane*16B implicit)
    const int ldst1 = 2048 + wave * 512;

    const int aoff = (waveRow + ml) * 32 + quad * 8;
    const int boff = (waveCol + ml) * 32 + quad * 8;

    for (int kt = 0; kt < FF; kt += 32) {
        __syncthreads();
        async16(gA0 + kt, &lds[0][ldst0]);
        async16(gA1 + kt, &lds[0][ldst1]);
        async16(gB0 + kt, &lds[2][ldst0]);
        async16(gB1 + kt, &lds[2][ldst1]);
        if (SIG) {
            async16(gAl0 + kt, &lds[1][ldst0]);
            async16(gAl1 + kt, &lds[1][ldst1]);
            async16(gBl0 + kt, &lds[3][ldst0]);
            async16(gBl1 + kt, &lds[3][ldst1]);
        }
        __syncthreads();

        short8 ah[4], bh[4];
#pragma unroll
        for (int i = 0; i < 4; i++) ah[i] = *(const short8*)&lds[0][aoff + i * 512];
#pragma unroll
        for (int j = 0; j < 4; j++) bh[j] = *(const short8*)&lds[2][boff + j * 512];

        if (!SIG) {
#pragma unroll
            for (int i = 0; i < 4; i++)
#pragma unroll
                for (int j = 0; j < 4; j++)
                    acc[i][j] = __builtin_amdgcn_mfma_f32_16x16x32_bf16(
                        ah[i], bh[j], acc[i][j], 0, 0, 0);
        } else {
            short8 al[4], bl[4];
#pragma unroll
            for (int i = 0; i < 4; i++) al[i] = *(const short8*)&lds[1][aoff + i * 512];
#pragma unroll
            for (int j = 0; j < 4; j++) bl[j] = *(const short8*)&lds[3][boff + j * 512];
#pragma unroll
            for (int i = 0; i < 4; i++)
#pragma unroll
                for (int j = 0; j < 4; j++) {
                    floatx4 c = acc[i][j];
                    c = __builtin_amdgcn_mfma_f32_16x16x32_bf16(ah[i], bh[j], c, 0, 0, 0);
                    c = __builtin_amdgcn_mfma_f32_16x16x32_bf16(ah[i], bl[j], c, 0, 0, 0);
                    c = __builtin_amdgcn_mfma_f32_16x16x32_bf16(al[i], bh[j], c, 0, 0, 0);
                    acc[i][j] = c;
                }
        }
    }

#pragma unroll
    for (int i = 0; i < 4; i++) {
        int rb = rowBase + waveRow + i * 16 + quad * 4;
#pragma unroll
        for (int j = 0; j < 4; j++) {
            int col = colBase + waveCol + j * 16 + ml;
#pragma unroll
            for (int r = 0; r < 4; r++) {
                int row = rb + r;
                if (row < NN) P[(size_t)row * 256 + col] = acc[i][j][r];
            }
        }
    }
}

// ---- epilogue: activations + small GEMMs -> Zm, Zs (N x 8 each) ------------
__global__ __launch_bounds__(256) void k_epi(const float* __restrict__ P,
        const float* __restrict__ Wm2, const float* __restrict__ Ws2,
        float* __restrict__ Zm, float* __restrict__ Zs) {
    __shared__ float xm[32 * 128];
    __shared__ float xs[32 * 128];
    __shared__ float wl[2048];
    const int tid = threadIdx.x;
    const int r0 = blockIdx.x * 32;

    for (int i = tid; i < 2048; i += 256) wl[i] = (i < 1024) ? Wm2[i] : Ws2[i - 1024];

#pragma unroll
    for (int p = 0; p < 16; ++p) {
        int idx = p * 256 + tid;            // 0..4095 = 32 rows x 128 k
        int r = idx >> 7, k = idx & 127;
        float u = P[(size_t)(r0 + r) * 256 + k];
        float v = P[(size_t)(r0 + r) * 256 + 128 + k];
        float m1 = u > 0.f ? u : __expf(u) - 1.f;   // elu
        float s1 = v > 0.f ? v : 0.f;               // relu
        float a1 = __expf(-s1);                     // exp(-gamma*sigma1)
        xm[idx] = m1 * a1;
        xs[idx] = s1 * a1 * a1;
    }
    __syncthreads();

#pragma unroll
    for (int p = 0; p < 2; ++p) {
        int task = p * 256 + tid;           // 0..511 = 32 rows x 16 outputs
        int r = task >> 4, oc = task & 15;
        const float* xv = (oc < 8) ? &xm[r * 128] : &xs[r * 128];
        const float* wv = &wl[(oc < 8) ? 0 : 1024];
        int c = oc & 7;
        float acc = 0.f;
#pragma unroll 8
        for (int k = 0; k < 128; ++k) acc += xv[k] * wv[k * 8 + c];
        int row = r0 + r;
        if (oc < 8) Zm[row * 8 + c] = acc;
        else        Zs[row * 8 + c] = acc;
    }
}

// ---- edge aggregation 1: hm += w1*Zm[src], hs += w2*Zs[src] ----------------
__global__ void k_agg1(const int* __restrict__ src, const int* __restrict__ dst,
        const float* __restrict__ w1, const float* __restrict__ w2,
        const float* __restrict__ Zm, const float* __restrict__ Zs,
        float* __restrict__ hm, float* __restrict__ hs) {
    int t = blockIdx.x * 256 + threadIdx.x;   // < EE*8
    int e = t >> 3, c = t & 7;
    int s = src[e], d = dst[e];
    atomicAdd(&hm[d * 8 + c], w1[e] * Zm[s * 8 + c]);
    atomicAdd(&hs[d * 8 + c], w2[e] * Zs[s * 8 + c]);
}

// ---- node transform: y = elu(hm)*exp(-relu(hs)); out = noise*sqrt(...) -----
__global__ void k_node(const float* __restrict__ hm, const float* __restrict__ hs,
        const float* __restrict__ noise, float* __restrict__ y,
        float* __restrict__ out) {
    int t = blockIdx.x * 256 + threadIdx.x;   // < NN*8
    float m = hm[t], s = hs[t];
    float miu2 = m > 0.f ? m : __expf(m) - 1.f;
    float s2 = s > 0.f ? s : 0.f;
    y[t] = miu2 * __expf(-s2);
    out[t] = noise[t] * sqrtf(s2 + 1e-8f);
}

// ---- edge aggregation 2: out += w1*y[src] ----------------------------------
__global__ void k_agg2(const int* __restrict__ src, const int* __restrict__ dst,
        const float* __restrict__ w1, const float* __restrict__ y,
        float* __restrict__ out) {
    int t = blockIdx.x * 256 + threadIdx.x;   // < EE*8
    int e = t >> 3, c = t & 7;
    atomicAdd(&out[dst[e] * 8 + c], w1[e] * y[src[e] * 8 + c]);
}

extern "C" void kernel_launch(void* const* d_in, const int* in_sizes, int n_in,
                              void* d_out, int out_size, void* d_ws, size_t ws_size,
                              hipStream_t stream) {
    (void)in_sizes; (void)n_in; (void)out_size; (void)ws_size;
    const float* feat  = (const float*)d_in[0];
    const int*   esrc  = (const int*)d_in[1];
    const int*   edst  = (const int*)d_in[2];
    const float* w1    = (const float*)d_in[3];
    const float* w2    = (const float*)d_in[4];
    const float* Wm1   = (const float*)d_in[5];
    const float* Ws1   = (const float*)d_in[6];
    const float* Wm2   = (const float*)d_in[7];
    const float* Ws2   = (const float*)d_in[8];
    const float* noise = (const float*)d_in[9];
    float* out = (float*)d_out;

    char* ws = (char*)d_ws;
    size_t off = 0;
    auto alloc = [&](size_t bytes) -> void* {
        void* p = ws + off;
        off += (bytes + 255) & ~(size_t)255;
        return p;
    };
    u16*   Ahi  = (u16*)alloc((size_t)PADM * FF * 2);
    u16*   Alo  = (u16*)alloc((size_t)PADM * FF * 2);
    u16*   WhiT = (u16*)alloc((size_t)256 * 512 * 2);
    u16*   WloT = (u16*)alloc((size_t)256 * 512 * 2);
    float* P    = (float*)alloc((size_t)PADM * 256 * 4);
    float* Zm   = (float*)alloc((size_t)NN * 8 * 4);
    float* Zs   = (float*)alloc((size_t)NN * 8 * 4);
    float* hm   = (float*)alloc((size_t)NN * 8 * 4);   // hm,hs contiguous
    float* hs   = (float*)alloc((size_t)NN * 8 * 4);
    float* yb   = (float*)alloc((size_t)NN * 8 * 4);
    (void)hs;

    hipMemsetAsync(hm, 0, (size_t)NN * 8 * 4 * 2, stream);   // zero hm+hs

    k_split_a<<<NN * FF / 4 / 256, 256, 0, stream>>>(feat, Ahi, Alo);
    k_split_w<<<512, 256, 0, stream>>>(Wm1, Ws1, WhiT, WloT);
    k_gemm<<<dim3(2, PADM / 128), 256, 0, stream>>>(Ahi, Alo, WhiT, WloT, P);
    k_epi<<<NN / 32, 256, 0, stream>>>(P, Wm2, Ws2, Zm, Zs);
    k_agg1<<<EE * 8 / 256, 256, 0, stream>>>(esrc, edst, w1, w2, Zm, Zs, hm, hs);
    k_node<<<NN * 8 / 256, 256, 0, stream>>>(hm, hs, noise, yb, out);
    k_agg2<<<EE * 8 / 256, 256, 0, stream>>>(esrc, edst, w1, yb, out);
}